// Round 11
// baseline (51.319 us; speedup 1.0000x reference)
//
#include <hip/hip_runtime.h>

// SoftErosion3D, connectivity=6, iterations=2, [2,1,256,256,256] f32.
//   iter1(x) = x^2 * prod(6 face nbrs), pad 1.0 ; out = iter1(iter1(im))
// Fused, no LDS, no barriers. Wave = full W row (64 lanes x float4); w+-1 via
// intra-wave shuffles. R10: TRANSPOSED MARCH — thread owns two D-PLANES
// (p,p+1) and marches along H, so every read/write stream advances +1KB/step
// (sequential DRAM pages) instead of +256KB/step. Structure identical to R8.

#define DD 256
#define HH 256
#define HW 65536
#define HT 16

typedef float nfloat4 __attribute__((ext_vector_type(4)));

__device__ __forceinline__ float wleft(float x) {     // lane-1's x ; lane0 -> 1.0
    float v = __shfl_up(x, 1, 64);
    return ((threadIdx.x & 63) == 0) ? 1.0f : v;
}
__device__ __forceinline__ float wright(float x) {    // lane+1's x ; lane63 -> 1.0
    float v = __shfl_down(x, 1, 64);
    return ((threadIdx.x & 63) == 63) ? 1.0f : v;
}
__device__ __forceinline__ float4 f4mul(float4 a, float4 b) {
    a.x *= b.x; a.y *= b.y; a.z *= b.z; a.w *= b.w; return a;
}
__device__ __forceinline__ float4 i1core(float4 c) {  // c^2 * W-neighbors
    float lw = wleft(c.w), rw = wright(c.x);
    float4 r;
    r.x = c.x * c.x * (lw  * c.y);
    r.y = c.y * c.y * (c.x * c.z);
    r.z = c.z * c.z * (c.y * c.w);
    r.w = c.w * c.w * (c.z * rw);
    return r;
}
__device__ __forceinline__ int hcl(int r) { return r < 0 ? 0 : (r > HH - 1 ? HH - 1 : r); }

__global__ __launch_bounds__(256) void erode6_fused(const float* __restrict__ in,
                                                    float* __restrict__ out) {
    const int bx  = blockIdx.x;
    const int swz = (bx & 7) * 128 + (bx >> 3);   // 1024 blocks, bijective XCD chunking

    const int cc = threadIdx.x & 63;              // f4 column, w = cc*4
    const int wv = __builtin_amdgcn_readfirstlane((int)(threadIdx.x >> 6));

    const int pblk = swz & 31;          // 32 plane-blocks of 8 planes
    const int hchk = (swz >> 5) & 15;   // 16 H-chunks of 16 rows
    const int b    = swz >> 9;          // batch

    const int p = pblk * 8 + wv * 2;    // own planes p, p+1
    const int S = hchk * HT;            // march rows S..S+15

    // owned-dim (D) boundary guards — mirror of R8's row guards
    const bool vbU = (p >= 1);
    const bool voU = (p >= 2);
    const bool vbD = (p + 2 <= DD - 1);
    const bool voD = (p + 3 <= DD - 1);
    const int plU  = vbU ? p - 1 : 0;
    const int plOU = voU ? p - 2 : 0;
    const int plD  = vbD ? p + 2 : DD - 1;
    const int plOD = voD ? p + 3 : DD - 1;

    const float* __restrict__ ip = in  + (size_t)b * (DD * HW);
    float* __restrict__       op = out + (size_t)b * (DD * HW);

    const float* pC0 = ip + (p     << 16) + (cc << 2);   // plane p
    const float* pC1 = ip + ((p+1) << 16) + (cc << 2);   // plane p+1
    const float* pBU = ip + (plU   << 16) + (cc << 2);   // plane p-1
    const float* pBD = ip + (plD   << 16) + (cc << 2);   // plane p+2
    const float* pOU = ip + (plOU  << 16) + (cc << 2);   // plane p-2
    const float* pOD = ip + (plOD  << 16) + (cc << 2);   // plane p+3
    float* pO0 = op + (p << 16) + (cc << 2);

// LD(stream, row): row stride is 256 floats = 1KB — sequential marching
#define LD(q, r) (*reinterpret_cast<const float4*>((q) + ((r) << 8)))

    const int Sm1 = S >= 1 ? S - 1 : 0;
    const int Sm2 = S >= 2 ? S - 2 : 0;

    // ---- prologue loads (row-rolling state per stream) ----
    float4 c0_m2 = LD(pC0, Sm2), c0_m1 = LD(pC0, Sm1);
    float4 c0_t  = LD(pC0, S), c0_t1 = LD(pC0, S + 1), c0_t2 = LD(pC0, S + 2);
    float4 c1_m2 = LD(pC1, Sm2), c1_m1 = LD(pC1, Sm1);
    float4 c1_t  = LD(pC1, S), c1_t1 = LD(pC1, S + 1), c1_t2 = LD(pC1, S + 2);
    float4 bu_m = LD(pBU, Sm1), bu_c = LD(pBU, S), bu_p = LD(pBU, S + 1);
    float4 bd_m = LD(pBD, Sm1), bd_c = LD(pBD, S), bd_p = LD(pBD, S + 1);
    float4 ou = LD(pOU, S), od = LD(pOD, S);

    // i*_m = iter1(row S-1, plane) — garbage at S==0, never used (guarded by fm)
    float4 i0_m = i1core(c0_m1);
    i0_m = f4mul(i0_m, c0_t);
    if (S >= 2) i0_m = f4mul(i0_m, c0_m2);
    if (vbU)    i0_m = f4mul(i0_m, bu_m);
    i0_m = f4mul(i0_m, c1_m1);

    float4 i1_m = i1core(c1_m1);
    i1_m = f4mul(i1_m, c1_t);
    if (S >= 2) i1_m = f4mul(i1_m, c1_m2);
    i1_m = f4mul(i1_m, c0_m1);
    if (vbD)    i1_m = f4mul(i1_m, bd_m);

    // i*_c = iter1(row S, plane)
    float4 i0_c = i1core(c0_t);
    if (S >= 1) i0_c = f4mul(i0_c, c0_m1);
    i0_c = f4mul(i0_c, c0_t1);
    if (vbU)    i0_c = f4mul(i0_c, bu_c);
    i0_c = f4mul(i0_c, c1_t);

    float4 i1_c = i1core(c1_t);
    if (S >= 1) i1_c = f4mul(i1_c, c1_m1);
    i1_c = f4mul(i1_c, c1_t1);
    i1_c = f4mul(i1_c, c0_t);
    if (vbD)    i1_c = f4mul(i1_c, bd_c);

#pragma unroll
    for (int k = 0; k < HT; ++k) {
        const int t = S + k;   // current output ROW

        // ---- 1-deep prefetch for next step (all streams +1KB) ----
        float4 pf_c0 = LD(pC0, hcl(t + 3)), pf_c1 = LD(pC1, hcl(t + 3));
        float4 pf_bu = LD(pBU, hcl(t + 2)), pf_bd = LD(pBD, hcl(t + 2));
        float4 pf_ou = LD(pOU, hcl(t + 1)), pf_od = LD(pOD, hcl(t + 1));

        const bool fm  = (t > 0);        // row t-1 exists
        const bool fp  = (t < HH - 1);   // row t+1 exists
        const bool fD2 = (t < HH - 2);   // row t+2 exists

        // ---- boundary-plane iter1 at row t ----
        float4 IbU = {1.f, 1.f, 1.f, 1.f};
        if (vbU) {
            IbU = i1core(bu_c);
            if (fm)  IbU = f4mul(IbU, bu_m);
            if (fp)  IbU = f4mul(IbU, bu_p);
            if (voU) IbU = f4mul(IbU, ou);
            IbU = f4mul(IbU, c0_t);
        }
        float4 IbD = {1.f, 1.f, 1.f, 1.f};
        if (vbD) {
            IbD = i1core(bd_c);
            if (fm)  IbD = f4mul(IbD, bd_m);
            if (fp)  IbD = f4mul(IbD, bd_p);
            IbD = f4mul(IbD, c1_t);
            if (voD) IbD = f4mul(IbD, od);
        }

        // ---- iter1(row t+1, own planes) ----
        float4 i0_p = i1core(c0_t1);
        i0_p = f4mul(i0_p, c0_t);
        if (fD2) i0_p = f4mul(i0_p, c0_t2);
        if (vbU) i0_p = f4mul(i0_p, bu_p);
        i0_p = f4mul(i0_p, c1_t1);

        float4 i1_p = i1core(c1_t1);
        i1_p = f4mul(i1_p, c1_t);
        if (fD2) i1_p = f4mul(i1_p, c1_t2);
        i1_p = f4mul(i1_p, c0_t1);
        if (vbD) i1_p = f4mul(i1_p, bd_p);

        // ---- iter2 outputs at row t ----
        float4 o0 = i1core(i0_c);
        if (fm) o0 = f4mul(o0, i0_m);
        if (fp) o0 = f4mul(o0, i0_p);
        o0 = f4mul(o0, IbU);
        o0 = f4mul(o0, i1_c);       // plane p+1's iter1 — in-register D-neighbor

        float4 o1 = i1core(i1_c);
        if (fm) o1 = f4mul(o1, i1_m);
        if (fp) o1 = f4mul(o1, i1_p);
        o1 = f4mul(o1, i0_c);
        o1 = f4mul(o1, IbD);

        nfloat4 v0 = {o0.x, o0.y, o0.z, o0.w};
        nfloat4 v1 = {o1.x, o1.y, o1.z, o1.w};
        __builtin_nontemporal_store(v0, reinterpret_cast<nfloat4*>(pO0 + (t << 8)));
        __builtin_nontemporal_store(v1, reinterpret_cast<nfloat4*>(pO0 + (t << 8) + HW));

        // ---- roll (register renaming under full unroll) ----
        i0_m = i0_c; i0_c = i0_p; i1_m = i1_c; i1_c = i1_p;
        c0_t = c0_t1; c0_t1 = c0_t2; c0_t2 = pf_c0;
        c1_t = c1_t1; c1_t1 = c1_t2; c1_t2 = pf_c1;
        bu_m = bu_c; bu_c = bu_p; bu_p = pf_bu;
        bd_m = bd_c; bd_c = bd_p; bd_p = pf_bd;
        ou = pf_ou; od = pf_od;
    }
#undef LD
}

extern "C" void kernel_launch(void* const* d_in, const int* in_sizes, int n_in,
                              void* d_out, int out_size, void* d_ws, size_t ws_size,
                              hipStream_t stream) {
    const float* in  = (const float*)d_in[0];
    float*       out = (float*)d_out;

    // 32 plane-blocks (8 planes) * 16 H-chunks (16 rows) * 2 batch = 1024
    dim3 block(256);
    dim3 grid(1024);
    erode6_fused<<<grid, block, 0, stream>>>(in, out);
}